// Round 3
// baseline (731.502 us; speedup 1.0000x reference)
//
#include <hip/hip_runtime.h>
#include <stdint.h>

// BitNet attention: int8-exact BitLinear GEMMs (MFMA i8) + bf16 flash attention (MFMA bf16).
// fp32 inputs / fp32 output. Internal q/k/v/P in bf16.
//  - GEMMs: TN, m97-style 128x128 tiles, global_load_lds width=16, XOR chunk swizzle
//    on the *global source* so LDS fragment reads are ~2-way bank aliased.
//    XCD-chunked blockIdx swizzle: each XCD owns a contiguous bn-range -> B panel L2-resident.
//  - MFMA 16x16 C/D layout: col(N)=lane&15, row(M)=(lane>>4)*4+reg.
//  - A/B frag (16x16x32 bf16): operand row = lane&15, 8 contiguous K elems at quad*8.
//  - k_attn: transposed-score scheme, Q-tile 64 / K-tile 64 (32 KB LDS -> 4 blocks/CU).
//    S^T = K·Q^T; O^T = Vt·P. P pack via v_cvt_pk_bf16_f32 (T12-pack), P move via the
//    PROVEN 8-shfl network (permlane32_swap orientation was wrong -> reverted),
//    defer-max rescale (T13), s_setprio around MFMA clusters (T5).

typedef float  f32x4 __attribute__((ext_vector_type(4)));
typedef short  s16x8 __attribute__((ext_vector_type(8)));
typedef int    i32x4 __attribute__((ext_vector_type(4)));

__device__ __forceinline__ uint16_t f2b(float f) {
  uint32_t u = __float_as_uint(f);
  return (uint16_t)((u + 0x7FFFu + ((u >> 16) & 1u)) >> 16);
}
__device__ __forceinline__ uint32_t cvt_pk_bf16(float lo, float hi) {
  uint32_t r;
  asm("v_cvt_pk_bf16_f32 %0, %1, %2" : "=v"(r) : "v"(lo), "v"(hi));
  return r;
}
__device__ __forceinline__ void gl_lds16(const void* g, void* l) {
  __builtin_amdgcn_global_load_lds((const __attribute__((address_space(1))) unsigned int*)g,
                                   (__attribute__((address_space(3))) unsigned int*)l, 16, 0, 0);
}
__device__ __forceinline__ f32x4 mfma_bf16(s16x8 a, s16x8 b, f32x4 c) {
  return __builtin_amdgcn_mfma_f32_16x16x32_bf16(a, b, c, 0, 0, 0);
}
__device__ __forceinline__ i32x4 mfma_i8(i32x4 a, i32x4 b, i32x4 c) {
  return __builtin_amdgcn_mfma_i32_16x16x64_i8(a, b, c, 0, 0, 0);
}

// ---------- per-row activation quant: absmax -> int8 (fp32 input) ----------
__global__ __launch_bounds__(256) void k_qact_f32(const float* __restrict__ x,
                                                  int8_t* __restrict__ xq, float* __restrict__ rs) {
  __shared__ float red[4];
  const int row = blockIdx.x, t = threadIdx.x;
  const float4* xr = (const float4*)(x + (size_t)row * 4096);
  float v[16];
  #pragma unroll
  for (int i = 0; i < 4; i++) {
    float4 f = xr[t + 256 * i];
    v[i*4+0] = f.x; v[i*4+1] = f.y; v[i*4+2] = f.z; v[i*4+3] = f.w;
  }
  float mx = 0.f;
  #pragma unroll
  for (int i = 0; i < 16; i++) mx = fmaxf(mx, fabsf(v[i]));
  for (int o = 1; o < 64; o <<= 1) mx = fmaxf(mx, __shfl_xor(mx, o));
  if ((t & 63) == 0) red[t >> 6] = mx;
  __syncthreads();
  mx = fmaxf(fmaxf(red[0], red[1]), fmaxf(red[2], red[3]));
  mx = fmaxf(mx, 1e-5f);
  const float a = 127.f / mx;
  if (t == 0) rs[row] = mx * (1.f / 127.f);
  uint32_t* dst = (uint32_t*)(xq + (size_t)row * 4096);
  #pragma unroll
  for (int i = 0; i < 4; i++) {
    uint32_t w = 0;
    #pragma unroll
    for (int j = 0; j < 4; j++) {
      float q = rintf(v[i*4+j] * a);
      q = fmaxf(-128.f, fminf(127.f, q));
      w |= ((uint32_t)((int)q & 255)) << (j * 8);
    }
    dst[t + 256 * i] = w;
  }
}

// ---------- fused weight abs-sum: block partials (no atomics) ----------
// Segments (blocks): Wq [0,1024), Wk [1024,1280), Wv [1280,1536), Wo [1536,2560).
// Each block covers 16384 floats.
__global__ __launch_bounds__(256) void k_abssum_part(const float* __restrict__ wq, const float* __restrict__ wk,
                                                     const float* __restrict__ wv, const float* __restrict__ wo,
                                                     double* __restrict__ part) {
  __shared__ double red[4];
  const int blk = blockIdx.x, t = threadIdx.x;
  const float* src; size_t base;
  if (blk < 1024)      { src = wq; base = (size_t)blk * 16384; }
  else if (blk < 1280) { src = wk; base = (size_t)(blk - 1024) * 16384; }
  else if (blk < 1536) { src = wv; base = (size_t)(blk - 1280) * 16384; }
  else                 { src = wo; base = (size_t)(blk - 1536) * 16384; }
  double s = 0.0;
  #pragma unroll
  for (int r = 0; r < 16; r++) {
    float4 f = *(const float4*)(src + base + r * 1024 + t * 4);
    s += (double)fabsf(f.x) + (double)fabsf(f.y) + (double)fabsf(f.z) + (double)fabsf(f.w);
  }
  for (int o = 1; o < 64; o <<= 1) s += __shfl_xor(s, o);
  if ((t & 63) == 0) red[t >> 6] = s;
  __syncthreads();
  if (t == 0) part[blk] = red[0] + red[1] + red[2] + red[3];
}

// ---------- reduce partials -> 4 sums (one block, wave w = segment w) ----------
__global__ __launch_bounds__(256) void k_reduce_sums(const double* __restrict__ part, double* __restrict__ sums) {
  const int w = threadIdx.x >> 6, lane = threadIdx.x & 63;
  const int s0 = (w == 0) ? 0 : (w == 1) ? 1024 : (w == 2) ? 1280 : 1536;
  const int s1 = (w == 0) ? 1024 : (w == 1) ? 1280 : (w == 2) ? 1536 : 2560;
  double s = 0.0;
  for (int i = s0 + lane; i < s1; i += 64) s += part[i];
  for (int o = 1; o < 64; o <<= 1) s += __shfl_xor(s, o);
  if (lane == 0) sums[w] = s;
}

// ---------- fused weight ternary quant (same segment map as abssum) ----------
__global__ __launch_bounds__(256) void k_quant_w_all(const float* __restrict__ wq, const float* __restrict__ wk,
                                                     const float* __restrict__ wv, const float* __restrict__ wo,
                                                     int8_t* __restrict__ wqkv, int8_t* __restrict__ woq,
                                                     const double* __restrict__ sums) {
  const int blk = blockIdx.x, t = threadIdx.x;
  const float* src; int8_t* dst; size_t base; int sidx; double ivn;
  if (blk < 1024)      { src = wq; dst = wqkv;                        base = (size_t)blk * 16384;          sidx = 0; ivn = 1.0 / 16777216.0; }
  else if (blk < 1280) { src = wk; dst = wqkv + (size_t)4096 * 4096;  base = (size_t)(blk - 1024) * 16384; sidx = 1; ivn = 1.0 / 4194304.0;  }
  else if (blk < 1536) { src = wv; dst = wqkv + (size_t)5120 * 4096;  base = (size_t)(blk - 1280) * 16384; sidx = 2; ivn = 1.0 / 4194304.0;  }
  else                 { src = wo; dst = woq;                         base = (size_t)(blk - 1536) * 16384; sidx = 3; ivn = 1.0 / 16777216.0; }
  const float ws = (float)fmax(sums[sidx] * ivn, 1e-5);
  #pragma unroll
  for (int r = 0; r < 16; r++) {
    size_t e = base + r * 1024 + t * 4;
    float4 f = *(const float4*)(src + e);
    float hv[4] = {f.x, f.y, f.z, f.w};
    uint32_t w = 0;
    #pragma unroll
    for (int j = 0; j < 4; j++) {
      float q = rintf(hv[j] / ws);
      q = fmaxf(-1.f, fminf(1.f, q));
      w |= ((uint32_t)((int)q & 255)) << (j * 8);
    }
    *(uint32_t*)(dst + e) = w;
  }
}

// ---------- int8 GEMM (TN): C[m][n] = sum_k A[m][k]*Bw[n][k] ----------
template<int MODE>
__global__ __launch_bounds__(256) void k_gemm_i8(const int8_t* __restrict__ A, const int8_t* __restrict__ Bw,
                                                 const float* __restrict__ rs, const double* __restrict__ sums,
                                                 uint16_t* __restrict__ qb, uint16_t* __restrict__ kb,
                                                 uint16_t* __restrict__ vb, float* __restrict__ outp) {
  __shared__ int8_t lA[16384];
  __shared__ int8_t lB[16384];
  // XCD-chunked bijective swizzle: dispatch id -> XCD is round-robin (%8); give each
  // XCD a contiguous nid chunk => contiguous bn range => B panel (<=3MB) L2-resident.
  constexpr int NX  = (MODE == 0) ? 48 : 32;
  constexpr int NWG = NX * 32;
  constexpr int CH  = NWG / 8;
  const int wg  = blockIdx.y * NX + blockIdx.x;
  const int nid = (wg & 7) * CH + (wg >> 3);
  const int bn = nid >> 5, bm = nid & 31;
  const int t = threadIdx.x, wave = t >> 6, lane = t & 63;
  const int quad = lane >> 4, l15 = lane & 15;
  const int wm = wave >> 1, wn = wave & 1;

  i32x4 acc[4][4];
  #pragma unroll
  for (int i = 0; i < 4; i++)
    #pragma unroll
    for (int j = 0; j < 4; j++) acc[i][j] = (i32x4){0, 0, 0, 0};

  const size_t arow0 = (size_t)bm * 128;
  const size_t brow0 = (size_t)bn * 128;

  for (int k0 = 0; k0 < 4096; k0 += 128) {
    #pragma unroll
    for (int r = 0; r < 4; r++) {
      int off = r * 4096 + wave * 1024 + lane * 16;
      int row = off >> 7;
      int pos = (off >> 4) & 7;
      int chunk = pos ^ (row & 7);
      gl_lds16(A  + (arow0 + row) * 4096 + k0 + chunk * 16, lA + r * 4096 + wave * 1024);
      gl_lds16(Bw + (brow0 + row) * 4096 + k0 + chunk * 16, lB + r * 4096 + wave * 1024);
    }
    __syncthreads();
    #pragma unroll
    for (int ks = 0; ks < 2; ks++) {
      i32x4 af[4], bf[4];
      #pragma unroll
      for (int i = 0; i < 4; i++) {
        int m = wm * 64 + i * 16 + l15;
        int c = ks * 4 + quad;
        af[i] = *(const i32x4*)(lA + m * 128 + (c ^ (m & 7)) * 16);
        int n = wn * 64 + i * 16 + l15;
        bf[i] = *(const i32x4*)(lB + n * 128 + (c ^ (n & 7)) * 16);
      }
      #pragma unroll
      for (int i = 0; i < 4; i++)
        #pragma unroll
        for (int j = 0; j < 4; j++)
          acc[i][j] = mfma_i8(af[i], bf[j], acc[i][j]);
    }
    __syncthreads();
  }

  float wsc; int sel = 0;
  if (MODE == 0) {
    if (bn < 32)      { wsc = (float)fmax(sums[0] * (1.0 / 16777216.0), 1e-5); sel = 0; }
    else if (bn < 40) { wsc = (float)fmax(sums[1] * (1.0 / 4194304.0),  1e-5); sel = 1; }
    else              { wsc = (float)fmax(sums[2] * (1.0 / 4194304.0),  1e-5); sel = 2; }
  } else {
    wsc = (float)fmax(sums[3] * (1.0 / 16777216.0), 1e-5);
  }
  #pragma unroll
  for (int i = 0; i < 4; i++) {
    #pragma unroll
    for (int r = 0; r < 4; r++) {
      int token = bm * 128 + wm * 64 + i * 16 + quad * 4 + r;
      float rv = rs[token] * wsc;
      #pragma unroll
      for (int j = 0; j < 4; j++) {
        int o = bn * 128 + wn * 64 + j * 16 + l15;
        float val = (float)acc[i][j][r] * rv;
        if (MODE == 0) {
          int b = token >> 11, s2 = token & 2047;
          if (sel == 0) {
            int hh = o >> 7, d = o & 127;
            qb[(((size_t)b * 32 + hh) * 2048 + s2) * 128 + d] = f2b(val * 0.08838834764831845f);
          } else if (sel == 1) {
            int o2 = o - 4096; int g = o2 >> 7, d = o2 & 127;
            kb[(((size_t)b * 8 + g) * 2048 + s2) * 128 + d] = f2b(val);
          } else {
            int o2 = o - 5120; int g = o2 >> 7, d = o2 & 127;
            vb[(((size_t)b * 8 + g) * 2048 + s2) * 128 + d] = f2b(val);
          }
        } else {
          outp[(size_t)token * 4096 + o] = val;
        }
      }
    }
  }
}

// ---------- V transpose: [g][s][d] -> [g][d][s] (bf16) ----------
__global__ __launch_bounds__(256) void k_transpose_v(const uint16_t* __restrict__ v, uint16_t* __restrict__ vt) {
  __shared__ uint16_t tile[64][72];
  const int bs = blockIdx.x * 64, bd = blockIdx.y * 64, g = blockIdx.z;
  const int t = threadIdx.x;
  const uint16_t* src = v + ((size_t)g * 2048 + bs) * 128 + bd;
  #pragma unroll
  for (int it = 0; it < 2; it++) {
    int r = (t >> 3) + it * 32;
    int c = (t & 7) * 8;
    uint4 u = *(const uint4*)(src + (size_t)r * 128 + c);
    uint16_t* p = &tile[r][c];
    p[0] = u.x & 0xffff; p[1] = u.x >> 16; p[2] = u.y & 0xffff; p[3] = u.y >> 16;
    p[4] = u.z & 0xffff; p[5] = u.z >> 16; p[6] = u.w & 0xffff; p[7] = u.w >> 16;
  }
  __syncthreads();
  uint16_t* dst = vt + ((size_t)g * 128 + bd) * 2048 + bs;
  #pragma unroll
  for (int it = 0; it < 2; it++) {
    int r = (t >> 3) + it * 32;
    int c = (t & 7) * 8;
    uint32_t w0 = tile[c+0][r] | ((uint32_t)tile[c+1][r] << 16);
    uint32_t w1 = tile[c+2][r] | ((uint32_t)tile[c+3][r] << 16);
    uint32_t w2 = tile[c+4][r] | ((uint32_t)tile[c+5][r] << 16);
    uint32_t w3 = tile[c+6][r] | ((uint32_t)tile[c+7][r] << 16);
    *(uint4*)(dst + (size_t)r * 2048 + c) = make_uint4(w0, w1, w2, w3);
  }
}

// ---------- flash attention, transposed-score, Q=64 / K=64 tiles ----------
// Grid (16, 64). Block p handles Q-tiles qt=p and qt=31-p (33 kt-iterations total).
// LDS: [0,16K) K tile (Q staging pre-loop), [16K,32K) Vt tile. 4 blocks/CU.
__global__ __launch_bounds__(256, 4) void k_attn(const uint16_t* __restrict__ qg, const uint16_t* __restrict__ kg,
                                                 const uint16_t* __restrict__ vtg, float* __restrict__ attn) {
  __shared__ char smem[32768];
  // XCD-chunked swizzle: each XCD owns 8 consecutive bh groups (2 kv heads -> 2MB K+V, L2-fit).
  const int wg  = blockIdx.y * 16 + blockIdx.x;
  const int nid = (wg & 7) * 128 + (wg >> 3);
  const int p = nid & 15, bh = nid >> 4;
  const int b = bh >> 5, h = bh & 31, kv = h >> 2;
  const int t = threadIdx.x, wave = t >> 6, lane = t & 63;
  const int quad = lane >> 4, l15 = lane & 15;

  const char* qbase = (const char*)(qg + (((size_t)b * 32 + h) * 2048) * 128);
  const char* ksrc  = (const char*)(kg + (((size_t)b * 8 + kv) * 2048) * 128);
  const char* vsrc  = (const char*)(vtg + (((size_t)b * 8 + kv) * 128) * 2048);

  for (int pass = 0; pass < 2; pass++) {
    const int qt = pass ? (31 - p) : p;

    __syncthreads();   // prior pass done with LDS
    // stage Q tile: 64 rows x 256 B into [0,16K)
    #pragma unroll
    for (int r = 0; r < 4; r++) {
      int off = r * 4096 + t * 16;
      int row = off >> 8, pos = (off >> 4) & 15;
      int chunk = pos ^ (row & 7);
      gl_lds16(qbase + (size_t)(qt * 64 + row) * 256 + chunk * 16, smem + off);
    }
    __syncthreads();
    s16x8 qf[4];
    #pragma unroll
    for (int ks = 0; ks < 4; ks++) {
      int n = wave * 16 + l15;           // this wave's q row
      int c = ks * 4 + quad;
      qf[ks] = *(const s16x8*)(smem + n * 256 + ((c ^ (n & 7))) * 16);
    }

    float Mx = -3.0e38f, Ls = 0.f;
    f32x4 Ov[8];
    #pragma unroll
    for (int mf = 0; mf < 8; mf++) Ov[mf] = (f32x4){0, 0, 0, 0};

    for (int kt = 0; kt <= qt; kt++) {
      __syncthreads();   // qf read done / prev iter LDS reads done
      #pragma unroll
      for (int r = 0; r < 4; r++) {
        int off = r * 4096 + t * 16;
        { int row = off >> 8, pos = (off >> 4) & 15, chunk = pos ^ (row & 7);
          gl_lds16(ksrc + (size_t)(kt * 64 + row) * 256 + chunk * 16, smem + off); }
        { int row = off >> 7, pos = (off >> 4) & 7, chunk = pos ^ (row & 7);
          gl_lds16(vsrc + (size_t)row * 4096 + kt * 128 + chunk * 16, smem + 16384 + off); }
      }
      __syncthreads();

      // ---- S^T = K·Q^T : C col=q(l15), row=key(quad*4+r) within mf block ----
      f32x4 sc[4];
      #pragma unroll
      for (int mf = 0; mf < 4; mf++) sc[mf] = (f32x4){0, 0, 0, 0};
      __builtin_amdgcn_s_setprio(1);
      #pragma unroll
      for (int ks = 0; ks < 4; ks++) {
        #pragma unroll
        for (int mf = 0; mf < 4; mf++) {
          int m = mf * 16 + l15;
          int c = ks * 4 + quad;
          s16x8 kf = *(const s16x8*)(smem + m * 256 + ((c ^ (m & 7))) * 16);
          sc[mf] = mfma_bf16(kf, qf[ks], sc[mf]);
        }
      }
      __builtin_amdgcn_s_setprio(0);

      if (kt == qt) {
        int qloc = wave * 16 + l15;
        #pragma unroll
        for (int mf = 0; mf < 4; mf++)
          #pragma unroll
          for (int r = 0; r < 4; r++) {
            int kloc = mf * 16 + quad * 4 + r;
            if (kloc > qloc) sc[mf][r] = -3.0e38f;
          }
      }

      // ---- online softmax over key dim (regs + cross-quad lanes) ----
      float x = sc[0][0];
      #pragma unroll
      for (int mf = 0; mf < 4; mf++)
        #pragma unroll
        for (int r = 0; r < 4; r++) x = fmaxf(x, sc[mf][r]);
      x = fmaxf(x, __shfl_xor(x, 16));
      x = fmaxf(x, __shfl_xor(x, 32));
      // T13 defer-max: skip the O/L rescale while the running max grows by <= 8
      // (P values then bounded by 2^8 = 256 — fine in bf16/f32 accumulation).
      if (!__all(x - Mx <= 8.f)) {
        float m2 = fmaxf(Mx, x);
        float al = exp2f(Mx - m2);
        Mx = m2;
        Ls *= al;
        #pragma unroll
        for (int mf = 0; mf < 8; mf++)
          #pragma unroll
          for (int r = 0; r < 4; r++) Ov[mf][r] *= al;
      }
      float s = 0.f;
      #pragma unroll
      for (int mf = 0; mf < 4; mf++)
        #pragma unroll
        for (int r = 0; r < 4; r++) {
          float pv = exp2f(sc[mf][r] - Mx);
          sc[mf][r] = pv;
          s += pv;
        }
      s += __shfl_xor(s, 16);
      s += __shfl_xor(s, 32);
      Ls += s;

      // ---- O^T += Vt·P : P C-layout -> B-layout via cross-quad shuffles ----
      // (proven network; pack via v_cvt_pk_bf16_f32 — same RNE as f2b, half the ops)
      #pragma unroll
      for (int ks = 0; ks < 2; ks++) {
        uint32_t pk[2][2];
        #pragma unroll
        for (int mfp = 0; mfp < 2; mfp++)
          #pragma unroll
          for (int pr = 0; pr < 2; pr++)
            pk[mfp][pr] = cvt_pk_bf16(sc[2*ks+mfp][2*pr], sc[2*ks+mfp][2*pr+1]);
        uint32_t pf[4];
        #pragma unroll
        for (int j2 = 0; j2 < 4; j2++) {
          int srcLane = ((quad & 1) * 2 + (j2 >> 1)) * 16 + l15;
          uint32_t a0 = __shfl(pk[0][j2 & 1], srcLane);
          uint32_t a1 = __shfl(pk[1][j2 & 1], srcLane);
          pf[j2] = (quad >= 2) ? a1 : a0;
        }
        s16x8 pfr = *(const s16x8*)&pf[0];
        __builtin_amdgcn_s_setprio(1);
        #pragma unroll
        for (int mf = 0; mf < 8; mf++) {
          int m = mf * 16 + l15;
          int c = ks * 4 + quad;
          s16x8 vf = *(const s16x8*)(smem + 16384 + m * 128 + ((c ^ (m & 7))) * 16);
          Ov[mf] = mfma_bf16(vf, pfr, Ov[mf]);
        }
        __builtin_amdgcn_s_setprio(0);
      }
    }

    // ---- write O^T (row=d=quad*4+reg within mf, col=q=l15) ----
    float inv = 1.f / Ls;
    size_t token = (size_t)b * 2048 + qt * 64 + wave * 16 + l15;
    float* obase = attn + token * 4096 + h * 128 + quad * 4;
    #pragma unroll
    for (int mf = 0; mf < 8; mf++) {
      float4 v4 = make_float4(Ov[mf][0] * inv, Ov[mf][1] * inv, Ov[mf][2] * inv, Ov[mf][3] * inv);
      *(float4*)(obase + mf * 16) = v4;
    }
  }
}

extern "C" void kernel_launch(void* const* d_in, const int* in_sizes, int n_in,
                              void* d_out, int out_size, void* d_ws, size_t ws_size,
                              hipStream_t stream) {
  (void)in_sizes; (void)out_size;
  if (n_in < 6) return;
  const float* hs = (const float*)d_in[0];
  const float* Wq = (const float*)d_in[2];
  const float* Wk = (const float*)d_in[3];
  const float* Wv = (const float*)d_in[4];
  const float* Wo = (const float*)d_in[5];
  float* out = (float*)d_out;

  char* p = (char*)d_ws;
  size_t off = 0;
  auto take = [&](size_t bytes) { char* r = p + off; off += (bytes + 255) & ~(size_t)255; return r; };
  int8_t*   xq1  = (int8_t*)  take((size_t)4096 * 4096);
  float*    rs1  = (float*)   take(4096 * 4);
  int8_t*   wqkv = (int8_t*)  take((size_t)6144 * 4096);
  int8_t*   woq  = (int8_t*)  take((size_t)4096 * 4096);
  uint16_t* qb   = (uint16_t*)take((size_t)2 * 32 * 2048 * 128 * 2);
  uint16_t* kb   = (uint16_t*)take((size_t)2 * 8 * 2048 * 128 * 2);
  uint16_t* vb   = (uint16_t*)take((size_t)2 * 8 * 2048 * 128 * 2);
  uint16_t* vtb  = (uint16_t*)take((size_t)2 * 8 * 2048 * 128 * 2);
  float*    attn = (float*)   take((size_t)4096 * 4096 * 4);
  int8_t*   xq2  = (int8_t*)  take((size_t)4096 * 4096);
  float*    rs2  = (float*)   take(4096 * 4);
  double*   part = (double*)  take(2560 * 8);
  double*   sums = (double*)  take(256);
  if (off > ws_size) return;

  k_abssum_part<<<2560, 256, 0, stream>>>(Wq, Wk, Wv, Wo, part);
  k_reduce_sums<<<1, 256, 0, stream>>>(part, sums);
  k_quant_w_all<<<2560, 256, 0, stream>>>(Wq, Wk, Wv, Wo, wqkv, woq, sums);
  k_qact_f32<<<4096, 256, 0, stream>>>(hs, xq1, rs1);
  k_gemm_i8<0><<<dim3(48, 32), 256, 0, stream>>>(xq1, wqkv, rs1, sums, qb, kb, vb, (float*)nullptr);
  k_transpose_v<<<dim3(32, 2, 16), 256, 0, stream>>>(vb, vtb);
  k_attn<<<dim3(16, 64), 256, 0, stream>>>(qb, kb, vtb, attn);
  k_qact_f32<<<4096, 256, 0, stream>>>(attn, xq2, rs2);
  k_gemm_i8<1><<<dim3(32, 32), 256, 0, stream>>>(xq2, woq, rs2, sums,
                                                 (uint16_t*)nullptr, (uint16_t*)nullptr, (uint16_t*)nullptr, out);
}

// Round 4
// 667.911 us; speedup vs baseline: 1.0952x; 1.0952x over previous
//
#include <hip/hip_runtime.h>
#include <stdint.h>

// BitNet attention: int8-exact BitLinear GEMMs (MFMA i8) + bf16 flash attention (MFMA bf16).
// fp32 inputs / fp32 output. Internal q/k/v/P in bf16.
//  - GEMMs: TN, m97-style 128x128 tiles, global_load_lds width=16, XOR chunk swizzle
//    on the *global source* so LDS fragment reads are ~2-way bank aliased.
//    NOTE: NO blockIdx swizzle — with NX=48/32 (both ≡0 mod 8), round-robin dispatch
//    already gives each XCD a fixed bn≡xcd(mod 8) set (B panels L2-resident) with
//    lockstep bm (A shared via L3). An XCD-chunk remap REGRESSED this (Round 3:
//    FETCH 209MB=5x ideal, GEMM0 167->183.5us). Keep the natural mapping.
//  - MFMA 16x16 C/D layout: col(N)=lane&15, row(M)=(lane>>4)*4+reg.
//  - A/B frag (16x16x32 bf16): operand row = lane&15, 8 contiguous K elems at quad*8.
//  - k_attn: transposed-score scheme, Q-tile 64 / K-tile 64 (32 KB LDS -> 4 blocks/CU).
//    S^T = K·Q^T; O^T = Vt·P. P pack via v_cvt_pk_bf16_f32 (T12-pack, RNE-identical to
//    f2b at half the VALU ops), P move via the PROVEN 8-shfl network, defer-max
//    rescale (T13), s_setprio around MFMA clusters (T5). absmax verified 0.03515625.

typedef float  f32x4 __attribute__((ext_vector_type(4)));
typedef short  s16x8 __attribute__((ext_vector_type(8)));
typedef int    i32x4 __attribute__((ext_vector_type(4)));

__device__ __forceinline__ uint16_t f2b(float f) {
  uint32_t u = __float_as_uint(f);
  return (uint16_t)((u + 0x7FFFu + ((u >> 16) & 1u)) >> 16);
}
__device__ __forceinline__ uint32_t cvt_pk_bf16(float lo, float hi) {
  uint32_t r;
  asm("v_cvt_pk_bf16_f32 %0, %1, %2" : "=v"(r) : "v"(lo), "v"(hi));
  return r;
}
__device__ __forceinline__ void gl_lds16(const void* g, void* l) {
  __builtin_amdgcn_global_load_lds((const __attribute__((address_space(1))) unsigned int*)g,
                                   (__attribute__((address_space(3))) unsigned int*)l, 16, 0, 0);
}
__device__ __forceinline__ f32x4 mfma_bf16(s16x8 a, s16x8 b, f32x4 c) {
  return __builtin_amdgcn_mfma_f32_16x16x32_bf16(a, b, c, 0, 0, 0);
}
__device__ __forceinline__ i32x4 mfma_i8(i32x4 a, i32x4 b, i32x4 c) {
  return __builtin_amdgcn_mfma_i32_16x16x64_i8(a, b, c, 0, 0, 0);
}

// ---------- per-row activation quant: absmax -> int8 (fp32 input) ----------
__global__ __launch_bounds__(256) void k_qact_f32(const float* __restrict__ x,
                                                  int8_t* __restrict__ xq, float* __restrict__ rs) {
  __shared__ float red[4];
  const int row = blockIdx.x, t = threadIdx.x;
  const float4* xr = (const float4*)(x + (size_t)row * 4096);
  float v[16];
  #pragma unroll
  for (int i = 0; i < 4; i++) {
    float4 f = xr[t + 256 * i];
    v[i*4+0] = f.x; v[i*4+1] = f.y; v[i*4+2] = f.z; v[i*4+3] = f.w;
  }
  float mx = 0.f;
  #pragma unroll
  for (int i = 0; i < 16; i++) mx = fmaxf(mx, fabsf(v[i]));
  for (int o = 1; o < 64; o <<= 1) mx = fmaxf(mx, __shfl_xor(mx, o));
  if ((t & 63) == 0) red[t >> 6] = mx;
  __syncthreads();
  mx = fmaxf(fmaxf(red[0], red[1]), fmaxf(red[2], red[3]));
  mx = fmaxf(mx, 1e-5f);
  const float a = 127.f / mx;
  if (t == 0) rs[row] = mx * (1.f / 127.f);
  uint32_t* dst = (uint32_t*)(xq + (size_t)row * 4096);
  #pragma unroll
  for (int i = 0; i < 4; i++) {
    uint32_t w = 0;
    #pragma unroll
    for (int j = 0; j < 4; j++) {
      float q = rintf(v[i*4+j] * a);
      q = fmaxf(-128.f, fminf(127.f, q));
      w |= ((uint32_t)((int)q & 255)) << (j * 8);
    }
    dst[t + 256 * i] = w;
  }
}

// ---------- fused weight abs-sum: block partials (no atomics) ----------
// Segments (blocks): Wq [0,1024), Wk [1024,1280), Wv [1280,1536), Wo [1536,2560).
// Each block covers 16384 floats.
__global__ __launch_bounds__(256) void k_abssum_part(const float* __restrict__ wq, const float* __restrict__ wk,
                                                     const float* __restrict__ wv, const float* __restrict__ wo,
                                                     double* __restrict__ part) {
  __shared__ double red[4];
  const int blk = blockIdx.x, t = threadIdx.x;
  const float* src; size_t base;
  if (blk < 1024)      { src = wq; base = (size_t)blk * 16384; }
  else if (blk < 1280) { src = wk; base = (size_t)(blk - 1024) * 16384; }
  else if (blk < 1536) { src = wv; base = (size_t)(blk - 1280) * 16384; }
  else                 { src = wo; base = (size_t)(blk - 1536) * 16384; }
  double s = 0.0;
  #pragma unroll
  for (int r = 0; r < 16; r++) {
    float4 f = *(const float4*)(src + base + r * 1024 + t * 4);
    s += (double)fabsf(f.x) + (double)fabsf(f.y) + (double)fabsf(f.z) + (double)fabsf(f.w);
  }
  for (int o = 1; o < 64; o <<= 1) s += __shfl_xor(s, o);
  if ((t & 63) == 0) red[t >> 6] = s;
  __syncthreads();
  if (t == 0) part[blk] = red[0] + red[1] + red[2] + red[3];
}

// ---------- reduce partials -> 4 sums (one block, wave w = segment w) ----------
__global__ __launch_bounds__(256) void k_reduce_sums(const double* __restrict__ part, double* __restrict__ sums) {
  const int w = threadIdx.x >> 6, lane = threadIdx.x & 63;
  const int s0 = (w == 0) ? 0 : (w == 1) ? 1024 : (w == 2) ? 1280 : 1536;
  const int s1 = (w == 0) ? 1024 : (w == 1) ? 1280 : (w == 2) ? 1536 : 2560;
  double s = 0.0;
  for (int i = s0 + lane; i < s1; i += 64) s += part[i];
  for (int o = 1; o < 64; o <<= 1) s += __shfl_xor(s, o);
  if (lane == 0) sums[w] = s;
}

// ---------- fused weight ternary quant (same segment map as abssum) ----------
__global__ __launch_bounds__(256) void k_quant_w_all(const float* __restrict__ wq, const float* __restrict__ wk,
                                                     const float* __restrict__ wv, const float* __restrict__ wo,
                                                     int8_t* __restrict__ wqkv, int8_t* __restrict__ woq,
                                                     const double* __restrict__ sums) {
  const int blk = blockIdx.x, t = threadIdx.x;
  const float* src; int8_t* dst; size_t base; int sidx; double ivn;
  if (blk < 1024)      { src = wq; dst = wqkv;                        base = (size_t)blk * 16384;          sidx = 0; ivn = 1.0 / 16777216.0; }
  else if (blk < 1280) { src = wk; dst = wqkv + (size_t)4096 * 4096;  base = (size_t)(blk - 1024) * 16384; sidx = 1; ivn = 1.0 / 4194304.0;  }
  else if (blk < 1536) { src = wv; dst = wqkv + (size_t)5120 * 4096;  base = (size_t)(blk - 1280) * 16384; sidx = 2; ivn = 1.0 / 4194304.0;  }
  else                 { src = wo; dst = woq;                         base = (size_t)(blk - 1536) * 16384; sidx = 3; ivn = 1.0 / 16777216.0; }
  const float ws = (float)fmax(sums[sidx] * ivn, 1e-5);
  #pragma unroll
  for (int r = 0; r < 16; r++) {
    size_t e = base + r * 1024 + t * 4;
    float4 f = *(const float4*)(src + e);
    float hv[4] = {f.x, f.y, f.z, f.w};
    uint32_t w = 0;
    #pragma unroll
    for (int j = 0; j < 4; j++) {
      float q = rintf(hv[j] / ws);
      q = fmaxf(-1.f, fminf(1.f, q));
      w |= ((uint32_t)((int)q & 255)) << (j * 8);
    }
    *(uint32_t*)(dst + e) = w;
  }
}

// ---------- int8 GEMM (TN): C[m][n] = sum_k A[m][k]*Bw[n][k] ----------
template<int MODE>
__global__ __launch_bounds__(256) void k_gemm_i8(const int8_t* __restrict__ A, const int8_t* __restrict__ Bw,
                                                 const float* __restrict__ rs, const double* __restrict__ sums,
                                                 uint16_t* __restrict__ qb, uint16_t* __restrict__ kb,
                                                 uint16_t* __restrict__ vb, float* __restrict__ outp) {
  __shared__ int8_t lA[16384];
  __shared__ int8_t lB[16384];
  // Natural mapping: bn=x, bm=y. Round-robin XCD assignment + NX%8==0 gives each XCD
  // a fixed small bn set (B panels L2-resident) and lockstep bm (A L3-shared).
  const int bn = blockIdx.x, bm = blockIdx.y;
  const int t = threadIdx.x, wave = t >> 6, lane = t & 63;
  const int quad = lane >> 4, l15 = lane & 15;
  const int wm = wave >> 1, wn = wave & 1;

  i32x4 acc[4][4];
  #pragma unroll
  for (int i = 0; i < 4; i++)
    #pragma unroll
    for (int j = 0; j < 4; j++) acc[i][j] = (i32x4){0, 0, 0, 0};

  const size_t arow0 = (size_t)bm * 128;
  const size_t brow0 = (size_t)bn * 128;

  for (int k0 = 0; k0 < 4096; k0 += 128) {
    #pragma unroll
    for (int r = 0; r < 4; r++) {
      int off = r * 4096 + wave * 1024 + lane * 16;
      int row = off >> 7;
      int pos = (off >> 4) & 7;
      int chunk = pos ^ (row & 7);
      gl_lds16(A  + (arow0 + row) * 4096 + k0 + chunk * 16, lA + r * 4096 + wave * 1024);
      gl_lds16(Bw + (brow0 + row) * 4096 + k0 + chunk * 16, lB + r * 4096 + wave * 1024);
    }
    __syncthreads();
    #pragma unroll
    for (int ks = 0; ks < 2; ks++) {
      i32x4 af[4], bf[4];
      #pragma unroll
      for (int i = 0; i < 4; i++) {
        int m = wm * 64 + i * 16 + l15;
        int c = ks * 4 + quad;
        af[i] = *(const i32x4*)(lA + m * 128 + (c ^ (m & 7)) * 16);
        int n = wn * 64 + i * 16 + l15;
        bf[i] = *(const i32x4*)(lB + n * 128 + (c ^ (n & 7)) * 16);
      }
      #pragma unroll
      for (int i = 0; i < 4; i++)
        #pragma unroll
        for (int j = 0; j < 4; j++)
          acc[i][j] = mfma_i8(af[i], bf[j], acc[i][j]);
    }
    __syncthreads();
  }

  float wsc; int sel = 0;
  if (MODE == 0) {
    if (bn < 32)      { wsc = (float)fmax(sums[0] * (1.0 / 16777216.0), 1e-5); sel = 0; }
    else if (bn < 40) { wsc = (float)fmax(sums[1] * (1.0 / 4194304.0),  1e-5); sel = 1; }
    else              { wsc = (float)fmax(sums[2] * (1.0 / 4194304.0),  1e-5); sel = 2; }
  } else {
    wsc = (float)fmax(sums[3] * (1.0 / 16777216.0), 1e-5);
  }
  #pragma unroll
  for (int i = 0; i < 4; i++) {
    #pragma unroll
    for (int r = 0; r < 4; r++) {
      int token = bm * 128 + wm * 64 + i * 16 + quad * 4 + r;
      float rv = rs[token] * wsc;
      #pragma unroll
      for (int j = 0; j < 4; j++) {
        int o = bn * 128 + wn * 64 + j * 16 + l15;
        float val = (float)acc[i][j][r] * rv;
        if (MODE == 0) {
          int b = token >> 11, s2 = token & 2047;
          if (sel == 0) {
            int hh = o >> 7, d = o & 127;
            qb[(((size_t)b * 32 + hh) * 2048 + s2) * 128 + d] = f2b(val * 0.08838834764831845f);
          } else if (sel == 1) {
            int o2 = o - 4096; int g = o2 >> 7, d = o2 & 127;
            kb[(((size_t)b * 8 + g) * 2048 + s2) * 128 + d] = f2b(val);
          } else {
            int o2 = o - 5120; int g = o2 >> 7, d = o2 & 127;
            vb[(((size_t)b * 8 + g) * 2048 + s2) * 128 + d] = f2b(val);
          }
        } else {
          outp[(size_t)token * 4096 + o] = val;
        }
      }
    }
  }
}

// ---------- V transpose: [g][s][d] -> [g][d][s] (bf16) ----------
__global__ __launch_bounds__(256) void k_transpose_v(const uint16_t* __restrict__ v, uint16_t* __restrict__ vt) {
  __shared__ uint16_t tile[64][72];
  const int bs = blockIdx.x * 64, bd = blockIdx.y * 64, g = blockIdx.z;
  const int t = threadIdx.x;
  const uint16_t* src = v + ((size_t)g * 2048 + bs) * 128 + bd;
  #pragma unroll
  for (int it = 0; it < 2; it++) {
    int r = (t >> 3) + it * 32;
    int c = (t & 7) * 8;
    uint4 u = *(const uint4*)(src + (size_t)r * 128 + c);
    uint16_t* p = &tile[r][c];
    p[0] = u.x & 0xffff; p[1] = u.x >> 16; p[2] = u.y & 0xffff; p[3] = u.y >> 16;
    p[4] = u.z & 0xffff; p[5] = u.z >> 16; p[6] = u.w & 0xffff; p[7] = u.w >> 16;
  }
  __syncthreads();
  uint16_t* dst = vt + ((size_t)g * 128 + bd) * 2048 + bs;
  #pragma unroll
  for (int it = 0; it < 2; it++) {
    int r = (t >> 3) + it * 32;
    int c = (t & 7) * 8;
    uint32_t w0 = tile[c+0][r] | ((uint32_t)tile[c+1][r] << 16);
    uint32_t w1 = tile[c+2][r] | ((uint32_t)tile[c+3][r] << 16);
    uint32_t w2 = tile[c+4][r] | ((uint32_t)tile[c+5][r] << 16);
    uint32_t w3 = tile[c+6][r] | ((uint32_t)tile[c+7][r] << 16);
    *(uint4*)(dst + (size_t)r * 2048 + c) = make_uint4(w0, w1, w2, w3);
  }
}

// ---------- flash attention, transposed-score, Q=64 / K=64 tiles ----------
// Grid (16, 64). Block p handles Q-tiles qt=p and qt=31-p (33 kt-iterations total).
// LDS: [0,16K) K tile (Q staging pre-loop), [16K,32K) Vt tile. 4 blocks/CU.
__global__ __launch_bounds__(256, 4) void k_attn(const uint16_t* __restrict__ qg, const uint16_t* __restrict__ kg,
                                                 const uint16_t* __restrict__ vtg, float* __restrict__ attn) {
  __shared__ char smem[32768];
  const int p = blockIdx.x, bh = blockIdx.y;
  const int b = bh >> 5, h = bh & 31, kv = h >> 2;
  const int t = threadIdx.x, wave = t >> 6, lane = t & 63;
  const int quad = lane >> 4, l15 = lane & 15;

  const char* qbase = (const char*)(qg + (((size_t)b * 32 + h) * 2048) * 128);
  const char* ksrc  = (const char*)(kg + (((size_t)b * 8 + kv) * 2048) * 128);
  const char* vsrc  = (const char*)(vtg + (((size_t)b * 8 + kv) * 128) * 2048);

  for (int pass = 0; pass < 2; pass++) {
    const int qt = pass ? (31 - p) : p;

    __syncthreads();   // prior pass done with LDS
    // stage Q tile: 64 rows x 256 B into [0,16K)
    #pragma unroll
    for (int r = 0; r < 4; r++) {
      int off = r * 4096 + t * 16;
      int row = off >> 8, pos = (off >> 4) & 15;
      int chunk = pos ^ (row & 7);
      gl_lds16(qbase + (size_t)(qt * 64 + row) * 256 + chunk * 16, smem + off);
    }
    __syncthreads();
    s16x8 qf[4];
    #pragma unroll
    for (int ks = 0; ks < 4; ks++) {
      int n = wave * 16 + l15;           // this wave's q row
      int c = ks * 4 + quad;
      qf[ks] = *(const s16x8*)(smem + n * 256 + ((c ^ (n & 7))) * 16);
    }

    float Mx = -3.0e38f, Ls = 0.f;
    f32x4 Ov[8];
    #pragma unroll
    for (int mf = 0; mf < 8; mf++) Ov[mf] = (f32x4){0, 0, 0, 0};

    for (int kt = 0; kt <= qt; kt++) {
      __syncthreads();   // qf read done / prev iter LDS reads done
      #pragma unroll
      for (int r = 0; r < 4; r++) {
        int off = r * 4096 + t * 16;
        { int row = off >> 8, pos = (off >> 4) & 15, chunk = pos ^ (row & 7);
          gl_lds16(ksrc + (size_t)(kt * 64 + row) * 256 + chunk * 16, smem + off); }
        { int row = off >> 7, pos = (off >> 4) & 7, chunk = pos ^ (row & 7);
          gl_lds16(vsrc + (size_t)row * 4096 + kt * 128 + chunk * 16, smem + 16384 + off); }
      }
      __syncthreads();

      // ---- S^T = K·Q^T : C col=q(l15), row=key(quad*4+r) within mf block ----
      f32x4 sc[4];
      #pragma unroll
      for (int mf = 0; mf < 4; mf++) sc[mf] = (f32x4){0, 0, 0, 0};
      __builtin_amdgcn_s_setprio(1);
      #pragma unroll
      for (int ks = 0; ks < 4; ks++) {
        #pragma unroll
        for (int mf = 0; mf < 4; mf++) {
          int m = mf * 16 + l15;
          int c = ks * 4 + quad;
          s16x8 kf = *(const s16x8*)(smem + m * 256 + ((c ^ (m & 7))) * 16);
          sc[mf] = mfma_bf16(kf, qf[ks], sc[mf]);
        }
      }
      __builtin_amdgcn_s_setprio(0);

      if (kt == qt) {
        int qloc = wave * 16 + l15;
        #pragma unroll
        for (int mf = 0; mf < 4; mf++)
          #pragma unroll
          for (int r = 0; r < 4; r++) {
            int kloc = mf * 16 + quad * 4 + r;
            if (kloc > qloc) sc[mf][r] = -3.0e38f;
          }
      }

      // ---- online softmax over key dim (regs + cross-quad lanes) ----
      float x = sc[0][0];
      #pragma unroll
      for (int mf = 0; mf < 4; mf++)
        #pragma unroll
        for (int r = 0; r < 4; r++) x = fmaxf(x, sc[mf][r]);
      x = fmaxf(x, __shfl_xor(x, 16));
      x = fmaxf(x, __shfl_xor(x, 32));
      // T13 defer-max: skip the O/L rescale while the running max grows by <= 8
      // (P values then bounded by 2^8 = 256 — fine in bf16/f32 accumulation).
      if (!__all(x - Mx <= 8.f)) {
        float m2 = fmaxf(Mx, x);
        float al = exp2f(Mx - m2);
        Mx = m2;
        Ls *= al;
        #pragma unroll
        for (int mf = 0; mf < 8; mf++)
          #pragma unroll
          for (int r = 0; r < 4; r++) Ov[mf][r] *= al;
      }
      float s = 0.f;
      #pragma unroll
      for (int mf = 0; mf < 4; mf++)
        #pragma unroll
        for (int r = 0; r < 4; r++) {
          float pv = exp2f(sc[mf][r] - Mx);
          sc[mf][r] = pv;
          s += pv;
        }
      s += __shfl_xor(s, 16);
      s += __shfl_xor(s, 32);
      Ls += s;

      // ---- O^T += Vt·P : P C-layout -> B-layout via cross-quad shuffles ----
      // (proven network; pack via v_cvt_pk_bf16_f32 — same RNE as f2b, half the ops)
      #pragma unroll
      for (int ks = 0; ks < 2; ks++) {
        uint32_t pk[2][2];
        #pragma unroll
        for (int mfp = 0; mfp < 2; mfp++)
          #pragma unroll
          for (int pr = 0; pr < 2; pr++)
            pk[mfp][pr] = cvt_pk_bf16(sc[2*ks+mfp][2*pr], sc[2*ks+mfp][2*pr+1]);
        uint32_t pf[4];
        #pragma unroll
        for (int j2 = 0; j2 < 4; j2++) {
          int srcLane = ((quad & 1) * 2 + (j2 >> 1)) * 16 + l15;
          uint32_t a0 = __shfl(pk[0][j2 & 1], srcLane);
          uint32_t a1 = __shfl(pk[1][j2 & 1], srcLane);
          pf[j2] = (quad >= 2) ? a1 : a0;
        }
        s16x8 pfr = *(const s16x8*)&pf[0];
        __builtin_amdgcn_s_setprio(1);
        #pragma unroll
        for (int mf = 0; mf < 8; mf++) {
          int m = mf * 16 + l15;
          int c = ks * 4 + quad;
          s16x8 vf = *(const s16x8*)(smem + 16384 + m * 128 + ((c ^ (m & 7))) * 16);
          Ov[mf] = mfma_bf16(vf, pfr, Ov[mf]);
        }
        __builtin_amdgcn_s_setprio(0);
      }
    }

    // ---- write O^T (row=d=quad*4+reg within mf, col=q=l15) ----
    float inv = 1.f / Ls;
    size_t token = (size_t)b * 2048 + qt * 64 + wave * 16 + l15;
    float* obase = attn + token * 4096 + h * 128 + quad * 4;
    #pragma unroll
    for (int mf = 0; mf < 8; mf++) {
      float4 v4 = make_float4(Ov[mf][0] * inv, Ov[mf][1] * inv, Ov[mf][2] * inv, Ov[mf][3] * inv);
      *(float4*)(obase + mf * 16) = v4;
    }
  }
}

extern "C" void kernel_launch(void* const* d_in, const int* in_sizes, int n_in,
                              void* d_out, int out_size, void* d_ws, size_t ws_size,
                              hipStream_t stream) {
  (void)in_sizes; (void)out_size;
  if (n_in < 6) return;
  const float* hs = (const float*)d_in[0];
  const float* Wq = (const float*)d_in[2];
  const float* Wk = (const float*)d_in[3];
  const float* Wv = (const float*)d_in[4];
  const float* Wo = (const float*)d_in[5];
  float* out = (float*)d_out;

  char* p = (char*)d_ws;
  size_t off = 0;
  auto take = [&](size_t bytes) { char* r = p + off; off += (bytes + 255) & ~(size_t)255; return r; };
  int8_t*   xq1  = (int8_t*)  take((size_t)4096 * 4096);
  float*    rs1  = (float*)   take(4096 * 4);
  int8_t*   wqkv = (int8_t*)  take((size_t)6144 * 4096);
  int8_t*   woq  = (int8_t*)  take((size_t)4096 * 4096);
  uint16_t* qb   = (uint16_t*)take((size_t)2 * 32 * 2048 * 128 * 2);
  uint16_t* kb   = (uint16_t*)take((size_t)2 * 8 * 2048 * 128 * 2);
  uint16_t* vb   = (uint16_t*)take((size_t)2 * 8 * 2048 * 128 * 2);
  uint16_t* vtb  = (uint16_t*)take((size_t)2 * 8 * 2048 * 128 * 2);
  float*    attn = (float*)   take((size_t)4096 * 4096 * 4);
  int8_t*   xq2  = (int8_t*)  take((size_t)4096 * 4096);
  float*    rs2  = (float*)   take(4096 * 4);
  double*   part = (double*)  take(2560 * 8);
  double*   sums = (double*)  take(256);
  if (off > ws_size) return;

  k_abssum_part<<<2560, 256, 0, stream>>>(Wq, Wk, Wv, Wo, part);
  k_reduce_sums<<<1, 256, 0, stream>>>(part, sums);
  k_quant_w_all<<<2560, 256, 0, stream>>>(Wq, Wk, Wv, Wo, wqkv, woq, sums);
  k_qact_f32<<<4096, 256, 0, stream>>>(hs, xq1, rs1);
  k_gemm_i8<0><<<dim3(48, 32), 256, 0, stream>>>(xq1, wqkv, rs1, sums, qb, kb, vb, (float*)nullptr);
  k_transpose_v<<<dim3(32, 2, 16), 256, 0, stream>>>(vb, vtb);
  k_attn<<<dim3(16, 64), 256, 0, stream>>>(qb, kb, vtb, attn);
  k_qact_f32<<<4096, 256, 0, stream>>>(attn, xq2, rs2);
  k_gemm_i8<1><<<dim3(32, 32), 256, 0, stream>>>(xq2, woq, rs2, sums,
                                                 (uint16_t*)nullptr, (uint16_t*)nullptr, (uint16_t*)nullptr, out);
}

// Round 5
// 655.884 us; speedup vs baseline: 1.1153x; 1.0183x over previous
//
#include <hip/hip_runtime.h>
#include <stdint.h>

// BitNet attention: int8-exact BitLinear GEMMs (MFMA i8) + bf16 flash attention (MFMA bf16).
// fp32 inputs / fp32 output. Internal q/k/v/P in bf16.
//  - GEMMs: TN, m97-style 128x128 tiles, global_load_lds width=16, XOR chunk swizzle
//    on the *global source* so LDS fragment reads are ~2-way bank aliased.
//    NOTE: NO blockIdx swizzle — with NX=48/32 (both ≡0 mod 8), round-robin dispatch
//    already gives each XCD a fixed bn≡xcd(mod 8) set (B panels L2-resident) with
//    lockstep bm (A shared via L3). An XCD-chunk remap REGRESSED this (Round 3:
//    FETCH 209MB=5x ideal, GEMM0 167->183.5us). Keep the natural mapping.
//  - MFMA 16x16 C/D layout: col(N)=lane&15, row(M)=(lane>>4)*4+reg.
//  - A/B frag (16x16x32 bf16): operand row = lane&15, 8 contiguous K elems at quad*8.
//  - k_attn: transposed-score, Q-tile 128 / K-tile 64, each wave owns 32 q rows
//    (two 16-row halves). K/V LDS fragments are read ONCE and used for BOTH halves
//    -> LDS-pipe demand per unit work halved (R4 showed LDS-throughput-bound:
//    32 ds_read_b128/wave/iter ≈ 6100cy/CU vs 640cy MFMA). Barriers/staging per
//    work also halve. Extra tail iter computes half0 fully masked (exact zeros,
//    branch-free via mask cond kt >= 2qt+hh). S^T = K·Q^T; O^T = Vt·P; P pack via
//    v_cvt_pk_bf16_f32, 8-shfl move network, defer-max (T13), setprio (T5).

typedef float  f32x4 __attribute__((ext_vector_type(4)));
typedef short  s16x8 __attribute__((ext_vector_type(8)));
typedef int    i32x4 __attribute__((ext_vector_type(4)));

__device__ __forceinline__ uint16_t f2b(float f) {
  uint32_t u = __float_as_uint(f);
  return (uint16_t)((u + 0x7FFFu + ((u >> 16) & 1u)) >> 16);
}
__device__ __forceinline__ uint32_t cvt_pk_bf16(float lo, float hi) {
  uint32_t r;
  asm("v_cvt_pk_bf16_f32 %0, %1, %2" : "=v"(r) : "v"(lo), "v"(hi));
  return r;
}
__device__ __forceinline__ void gl_lds16(const void* g, void* l) {
  __builtin_amdgcn_global_load_lds((const __attribute__((address_space(1))) unsigned int*)g,
                                   (__attribute__((address_space(3))) unsigned int*)l, 16, 0, 0);
}
__device__ __forceinline__ f32x4 mfma_bf16(s16x8 a, s16x8 b, f32x4 c) {
  return __builtin_amdgcn_mfma_f32_16x16x32_bf16(a, b, c, 0, 0, 0);
}
__device__ __forceinline__ i32x4 mfma_i8(i32x4 a, i32x4 b, i32x4 c) {
  return __builtin_amdgcn_mfma_i32_16x16x64_i8(a, b, c, 0, 0, 0);
}

// ---------- per-row activation quant: absmax -> int8 (fp32 input) ----------
__global__ __launch_bounds__(256) void k_qact_f32(const float* __restrict__ x,
                                                  int8_t* __restrict__ xq, float* __restrict__ rs) {
  __shared__ float red[4];
  const int row = blockIdx.x, t = threadIdx.x;
  const float4* xr = (const float4*)(x + (size_t)row * 4096);
  float v[16];
  #pragma unroll
  for (int i = 0; i < 4; i++) {
    float4 f = xr[t + 256 * i];
    v[i*4+0] = f.x; v[i*4+1] = f.y; v[i*4+2] = f.z; v[i*4+3] = f.w;
  }
  float mx = 0.f;
  #pragma unroll
  for (int i = 0; i < 16; i++) mx = fmaxf(mx, fabsf(v[i]));
  for (int o = 1; o < 64; o <<= 1) mx = fmaxf(mx, __shfl_xor(mx, o));
  if ((t & 63) == 0) red[t >> 6] = mx;
  __syncthreads();
  mx = fmaxf(fmaxf(red[0], red[1]), fmaxf(red[2], red[3]));
  mx = fmaxf(mx, 1e-5f);
  const float a = 127.f / mx;
  if (t == 0) rs[row] = mx * (1.f / 127.f);
  uint32_t* dst = (uint32_t*)(xq + (size_t)row * 4096);
  #pragma unroll
  for (int i = 0; i < 4; i++) {
    uint32_t w = 0;
    #pragma unroll
    for (int j = 0; j < 4; j++) {
      float q = rintf(v[i*4+j] * a);
      q = fmaxf(-128.f, fminf(127.f, q));
      w |= ((uint32_t)((int)q & 255)) << (j * 8);
    }
    dst[t + 256 * i] = w;
  }
}

// ---------- fused weight abs-sum: block partials (no atomics) ----------
// Segments (blocks): Wq [0,1024), Wk [1024,1280), Wv [1280,1536), Wo [1536,2560).
// Each block covers 16384 floats.
__global__ __launch_bounds__(256) void k_abssum_part(const float* __restrict__ wq, const float* __restrict__ wk,
                                                     const float* __restrict__ wv, const float* __restrict__ wo,
                                                     double* __restrict__ part) {
  __shared__ double red[4];
  const int blk = blockIdx.x, t = threadIdx.x;
  const float* src; size_t base;
  if (blk < 1024)      { src = wq; base = (size_t)blk * 16384; }
  else if (blk < 1280) { src = wk; base = (size_t)(blk - 1024) * 16384; }
  else if (blk < 1536) { src = wv; base = (size_t)(blk - 1280) * 16384; }
  else                 { src = wo; base = (size_t)(blk - 1536) * 16384; }
  double s = 0.0;
  #pragma unroll
  for (int r = 0; r < 16; r++) {
    float4 f = *(const float4*)(src + base + r * 1024 + t * 4);
    s += (double)fabsf(f.x) + (double)fabsf(f.y) + (double)fabsf(f.z) + (double)fabsf(f.w);
  }
  for (int o = 1; o < 64; o <<= 1) s += __shfl_xor(s, o);
  if ((t & 63) == 0) red[t >> 6] = s;
  __syncthreads();
  if (t == 0) part[blk] = red[0] + red[1] + red[2] + red[3];
}

// ---------- reduce partials -> 4 sums (one block, wave w = segment w) ----------
__global__ __launch_bounds__(256) void k_reduce_sums(const double* __restrict__ part, double* __restrict__ sums) {
  const int w = threadIdx.x >> 6, lane = threadIdx.x & 63;
  const int s0 = (w == 0) ? 0 : (w == 1) ? 1024 : (w == 2) ? 1280 : 1536;
  const int s1 = (w == 0) ? 1024 : (w == 1) ? 1280 : (w == 2) ? 1536 : 2560;
  double s = 0.0;
  for (int i = s0 + lane; i < s1; i += 64) s += part[i];
  for (int o = 1; o < 64; o <<= 1) s += __shfl_xor(s, o);
  if (lane == 0) sums[w] = s;
}

// ---------- fused weight ternary quant (same segment map as abssum) ----------
__global__ __launch_bounds__(256) void k_quant_w_all(const float* __restrict__ wq, const float* __restrict__ wk,
                                                     const float* __restrict__ wv, const float* __restrict__ wo,
                                                     int8_t* __restrict__ wqkv, int8_t* __restrict__ woq,
                                                     const double* __restrict__ sums) {
  const int blk = blockIdx.x, t = threadIdx.x;
  const float* src; int8_t* dst; size_t base; int sidx; double ivn;
  if (blk < 1024)      { src = wq; dst = wqkv;                        base = (size_t)blk * 16384;          sidx = 0; ivn = 1.0 / 16777216.0; }
  else if (blk < 1280) { src = wk; dst = wqkv + (size_t)4096 * 4096;  base = (size_t)(blk - 1024) * 16384; sidx = 1; ivn = 1.0 / 4194304.0;  }
  else if (blk < 1536) { src = wv; dst = wqkv + (size_t)5120 * 4096;  base = (size_t)(blk - 1280) * 16384; sidx = 2; ivn = 1.0 / 4194304.0;  }
  else                 { src = wo; dst = woq;                         base = (size_t)(blk - 1536) * 16384; sidx = 3; ivn = 1.0 / 16777216.0; }
  const float ws = (float)fmax(sums[sidx] * ivn, 1e-5);
  #pragma unroll
  for (int r = 0; r < 16; r++) {
    size_t e = base + r * 1024 + t * 4;
    float4 f = *(const float4*)(src + e);
    float hv[4] = {f.x, f.y, f.z, f.w};
    uint32_t w = 0;
    #pragma unroll
    for (int j = 0; j < 4; j++) {
      float q = rintf(hv[j] / ws);
      q = fmaxf(-1.f, fminf(1.f, q));
      w |= ((uint32_t)((int)q & 255)) << (j * 8);
    }
    *(uint32_t*)(dst + e) = w;
  }
}

// ---------- int8 GEMM (TN): C[m][n] = sum_k A[m][k]*Bw[n][k] ----------
template<int MODE>
__global__ __launch_bounds__(256) void k_gemm_i8(const int8_t* __restrict__ A, const int8_t* __restrict__ Bw,
                                                 const float* __restrict__ rs, const double* __restrict__ sums,
                                                 uint16_t* __restrict__ qb, uint16_t* __restrict__ kb,
                                                 uint16_t* __restrict__ vb, float* __restrict__ outp) {
  __shared__ int8_t lA[16384];
  __shared__ int8_t lB[16384];
  // Natural mapping: bn=x, bm=y. Round-robin XCD assignment + NX%8==0 gives each XCD
  // a fixed small bn set (B panels L2-resident) and lockstep bm (A L3-shared).
  const int bn = blockIdx.x, bm = blockIdx.y;
  const int t = threadIdx.x, wave = t >> 6, lane = t & 63;
  const int quad = lane >> 4, l15 = lane & 15;
  const int wm = wave >> 1, wn = wave & 1;

  i32x4 acc[4][4];
  #pragma unroll
  for (int i = 0; i < 4; i++)
    #pragma unroll
    for (int j = 0; j < 4; j++) acc[i][j] = (i32x4){0, 0, 0, 0};

  const size_t arow0 = (size_t)bm * 128;
  const size_t brow0 = (size_t)bn * 128;

  for (int k0 = 0; k0 < 4096; k0 += 128) {
    #pragma unroll
    for (int r = 0; r < 4; r++) {
      int off = r * 4096 + wave * 1024 + lane * 16;
      int row = off >> 7;
      int pos = (off >> 4) & 7;
      int chunk = pos ^ (row & 7);
      gl_lds16(A  + (arow0 + row) * 4096 + k0 + chunk * 16, lA + r * 4096 + wave * 1024);
      gl_lds16(Bw + (brow0 + row) * 4096 + k0 + chunk * 16, lB + r * 4096 + wave * 1024);
    }
    __syncthreads();
    #pragma unroll
    for (int ks = 0; ks < 2; ks++) {
      i32x4 af[4], bf[4];
      #pragma unroll
      for (int i = 0; i < 4; i++) {
        int m = wm * 64 + i * 16 + l15;
        int c = ks * 4 + quad;
        af[i] = *(const i32x4*)(lA + m * 128 + (c ^ (m & 7)) * 16);
        int n = wn * 64 + i * 16 + l15;
        bf[i] = *(const i32x4*)(lB + n * 128 + (c ^ (n & 7)) * 16);
      }
      #pragma unroll
      for (int i = 0; i < 4; i++)
        #pragma unroll
        for (int j = 0; j < 4; j++)
          acc[i][j] = mfma_i8(af[i], bf[j], acc[i][j]);
    }
    __syncthreads();
  }

  float wsc; int sel = 0;
  if (MODE == 0) {
    if (bn < 32)      { wsc = (float)fmax(sums[0] * (1.0 / 16777216.0), 1e-5); sel = 0; }
    else if (bn < 40) { wsc = (float)fmax(sums[1] * (1.0 / 4194304.0),  1e-5); sel = 1; }
    else              { wsc = (float)fmax(sums[2] * (1.0 / 4194304.0),  1e-5); sel = 2; }
  } else {
    wsc = (float)fmax(sums[3] * (1.0 / 16777216.0), 1e-5);
  }
  #pragma unroll
  for (int i = 0; i < 4; i++) {
    #pragma unroll
    for (int r = 0; r < 4; r++) {
      int token = bm * 128 + wm * 64 + i * 16 + quad * 4 + r;
      float rv = rs[token] * wsc;
      #pragma unroll
      for (int j = 0; j < 4; j++) {
        int o = bn * 128 + wn * 64 + j * 16 + l15;
        float val = (float)acc[i][j][r] * rv;
        if (MODE == 0) {
          int b = token >> 11, s2 = token & 2047;
          if (sel == 0) {
            int hh = o >> 7, d = o & 127;
            qb[(((size_t)b * 32 + hh) * 2048 + s2) * 128 + d] = f2b(val * 0.08838834764831845f);
          } else if (sel == 1) {
            int o2 = o - 4096; int g = o2 >> 7, d = o2 & 127;
            kb[(((size_t)b * 8 + g) * 2048 + s2) * 128 + d] = f2b(val);
          } else {
            int o2 = o - 5120; int g = o2 >> 7, d = o2 & 127;
            vb[(((size_t)b * 8 + g) * 2048 + s2) * 128 + d] = f2b(val);
          }
        } else {
          outp[(size_t)token * 4096 + o] = val;
        }
      }
    }
  }
}

// ---------- V transpose: [g][s][d] -> [g][d][s] (bf16) ----------
__global__ __launch_bounds__(256) void k_transpose_v(const uint16_t* __restrict__ v, uint16_t* __restrict__ vt) {
  __shared__ uint16_t tile[64][72];
  const int bs = blockIdx.x * 64, bd = blockIdx.y * 64, g = blockIdx.z;
  const int t = threadIdx.x;
  const uint16_t* src = v + ((size_t)g * 2048 + bs) * 128 + bd;
  #pragma unroll
  for (int it = 0; it < 2; it++) {
    int r = (t >> 3) + it * 32;
    int c = (t & 7) * 8;
    uint4 u = *(const uint4*)(src + (size_t)r * 128 + c);
    uint16_t* p = &tile[r][c];
    p[0] = u.x & 0xffff; p[1] = u.x >> 16; p[2] = u.y & 0xffff; p[3] = u.y >> 16;
    p[4] = u.z & 0xffff; p[5] = u.z >> 16; p[6] = u.w & 0xffff; p[7] = u.w >> 16;
  }
  __syncthreads();
  uint16_t* dst = vt + ((size_t)g * 128 + bd) * 2048 + bs;
  #pragma unroll
  for (int it = 0; it < 2; it++) {
    int r = (t >> 3) + it * 32;
    int c = (t & 7) * 8;
    uint32_t w0 = tile[c+0][r] | ((uint32_t)tile[c+1][r] << 16);
    uint32_t w1 = tile[c+2][r] | ((uint32_t)tile[c+3][r] << 16);
    uint32_t w2 = tile[c+4][r] | ((uint32_t)tile[c+5][r] << 16);
    uint32_t w3 = tile[c+6][r] | ((uint32_t)tile[c+7][r] << 16);
    *(uint4*)(dst + (size_t)r * 2048 + c) = make_uint4(w0, w1, w2, w3);
  }
}

// ---------- flash attention, transposed-score, Q=128 / K=64 tiles ----------
// Grid (8, 64). Block p handles Q-tiles qt=p and qt=15-p (34 kt-iterations total).
// Each wave owns 32 q rows as two 16-row halves; kf/vf fragments read once, used
// for both halves (LDS demand per work halved vs R4). LDS: Q staged across the
// full 32 KB pre-loop; per-iter [0,16K) K tile, [16K,32K) Vt tile. 2 blocks/CU.
__global__ __launch_bounds__(256, 2) void k_attn(const uint16_t* __restrict__ qg, const uint16_t* __restrict__ kg,
                                                 const uint16_t* __restrict__ vtg, float* __restrict__ attn) {
  __shared__ char smem[32768];
  const int p = blockIdx.x, bh = blockIdx.y;
  const int b = bh >> 5, h = bh & 31, kv = h >> 2;
  const int t = threadIdx.x, wave = t >> 6, lane = t & 63;
  const int quad = lane >> 4, l15 = lane & 15;

  const char* qbase = (const char*)(qg + (((size_t)b * 32 + h) * 2048) * 128);
  const char* ksrc  = (const char*)(kg + (((size_t)b * 8 + kv) * 2048) * 128);
  const char* vsrc  = (const char*)(vtg + (((size_t)b * 8 + kv) * 128) * 2048);

  for (int pass = 0; pass < 2; pass++) {
    const int qt = pass ? (15 - p) : p;

    __syncthreads();   // prior pass done with LDS
    // stage Q tile: 128 rows x 256 B = 32 KB
    #pragma unroll
    for (int r = 0; r < 8; r++) {
      int off = r * 4096 + t * 16;
      int row = off >> 8, pos = (off >> 4) & 15;
      int chunk = pos ^ (row & 7);
      gl_lds16(qbase + (size_t)(qt * 128 + row) * 256 + chunk * 16, smem + off);
    }
    __syncthreads();
    s16x8 qf[2][4];
    #pragma unroll
    for (int hh = 0; hh < 2; hh++)
      #pragma unroll
      for (int ks = 0; ks < 4; ks++) {
        int n = hh * 64 + wave * 16 + l15;   // this wave's q row (half hh)
        int c = ks * 4 + quad;
        qf[hh][ks] = *(const s16x8*)(smem + n * 256 + ((c ^ (n & 7))) * 16);
      }

    float Mx[2] = {-3.0e38f, -3.0e38f};
    float Ls[2] = {0.f, 0.f};
    f32x4 Ov[2][8];
    #pragma unroll
    for (int hh = 0; hh < 2; hh++)
      #pragma unroll
      for (int mf = 0; mf < 8; mf++) Ov[hh][mf] = (f32x4){0, 0, 0, 0};

    const int nkt = 2 * qt + 1;   // last K-tile index (half1's diagonal)
    for (int kt = 0; kt <= nkt; kt++) {
      __syncthreads();   // qf read done / prev iter LDS reads done
      #pragma unroll
      for (int r = 0; r < 4; r++) {
        int off = r * 4096 + t * 16;
        { int row = off >> 8, pos = (off >> 4) & 15, chunk = pos ^ (row & 7);
          gl_lds16(ksrc + (size_t)(kt * 64 + row) * 256 + chunk * 16, smem + off); }
        { int row = off >> 7, pos = (off >> 4) & 7, chunk = pos ^ (row & 7);
          gl_lds16(vsrc + (size_t)row * 4096 + kt * 128 + chunk * 16, smem + 16384 + off); }
      }
      __syncthreads();

      // ---- S^T = K·Q^T for both halves: kf read once, used twice ----
      f32x4 sc[2][4];
      #pragma unroll
      for (int hh = 0; hh < 2; hh++)
        #pragma unroll
        for (int mf = 0; mf < 4; mf++) sc[hh][mf] = (f32x4){0, 0, 0, 0};
      __builtin_amdgcn_s_setprio(1);
      #pragma unroll
      for (int ks = 0; ks < 4; ks++) {
        #pragma unroll
        for (int mf = 0; mf < 4; mf++) {
          int m = mf * 16 + l15;
          int c = ks * 4 + quad;
          s16x8 kf = *(const s16x8*)(smem + m * 256 + ((c ^ (m & 7))) * 16);
          sc[0][mf] = mfma_bf16(kf, qf[0][ks], sc[0][mf]);
          sc[1][mf] = mfma_bf16(kf, qf[1][ks], sc[1][mf]);
        }
      }
      __builtin_amdgcn_s_setprio(0);

      // ---- causal mask (local coords). kt==2qt+hh: diagonal; beyond: fully masked
      //      (only half0 at kt=2qt+1 — contributes exact zeros, branch-free). ----
      #pragma unroll
      for (int hh = 0; hh < 2; hh++) {
        if (kt >= 2 * qt + hh) {
          int qloc = hh * 64 + wave * 16 + l15;
          int kb = (kt - 2 * qt) * 64;
          #pragma unroll
          for (int mf = 0; mf < 4; mf++)
            #pragma unroll
            for (int r = 0; r < 4; r++) {
              int kloc = kb + mf * 16 + quad * 4 + r;
              if (kloc > qloc) sc[hh][mf][r] = -3.0e38f;
            }
        }
      }

      // ---- online softmax per half (regs + cross-quad lanes) ----
      #pragma unroll
      for (int hh = 0; hh < 2; hh++) {
        float x = sc[hh][0][0];
        #pragma unroll
        for (int mf = 0; mf < 4; mf++)
          #pragma unroll
          for (int r = 0; r < 4; r++) x = fmaxf(x, sc[hh][mf][r]);
        x = fmaxf(x, __shfl_xor(x, 16));
        x = fmaxf(x, __shfl_xor(x, 32));
        // T13 defer-max: skip the O/L rescale while the running max grows by <= 8.
        if (!__all(x - Mx[hh] <= 8.f)) {
          float m2 = fmaxf(Mx[hh], x);
          float al = exp2f(Mx[hh] - m2);
          Mx[hh] = m2;
          Ls[hh] *= al;
          #pragma unroll
          for (int mf = 0; mf < 8; mf++)
            #pragma unroll
            for (int r = 0; r < 4; r++) Ov[hh][mf][r] *= al;
        }
        float s = 0.f;
        #pragma unroll
        for (int mf = 0; mf < 4; mf++)
          #pragma unroll
          for (int r = 0; r < 4; r++) {
            float pv = exp2f(sc[hh][mf][r] - Mx[hh]);
            sc[hh][mf][r] = pv;
            s += pv;
          }
        s += __shfl_xor(s, 16);
        s += __shfl_xor(s, 32);
        Ls[hh] += s;
      }

      // ---- O^T += Vt·P both halves: vf read once, used twice ----
      #pragma unroll
      for (int ks = 0; ks < 2; ks++) {
        uint32_t pfw[2][4];
        #pragma unroll
        for (int hh = 0; hh < 2; hh++) {
          uint32_t pk[2][2];
          #pragma unroll
          for (int mfp = 0; mfp < 2; mfp++)
            #pragma unroll
            for (int pr = 0; pr < 2; pr++)
              pk[mfp][pr] = cvt_pk_bf16(sc[hh][2*ks+mfp][2*pr], sc[hh][2*ks+mfp][2*pr+1]);
          #pragma unroll
          for (int j2 = 0; j2 < 4; j2++) {
            int srcLane = ((quad & 1) * 2 + (j2 >> 1)) * 16 + l15;
            uint32_t a0 = __shfl(pk[0][j2 & 1], srcLane);
            uint32_t a1 = __shfl(pk[1][j2 & 1], srcLane);
            pfw[hh][j2] = (quad >= 2) ? a1 : a0;
          }
        }
        s16x8 pfr0 = *(const s16x8*)&pfw[0][0];
        s16x8 pfr1 = *(const s16x8*)&pfw[1][0];
        __builtin_amdgcn_s_setprio(1);
        #pragma unroll
        for (int mf = 0; mf < 8; mf++) {
          int m = mf * 16 + l15;
          int c = ks * 4 + quad;
          s16x8 vf = *(const s16x8*)(smem + 16384 + m * 128 + ((c ^ (m & 7))) * 16);
          Ov[0][mf] = mfma_bf16(vf, pfr0, Ov[0][mf]);
          Ov[1][mf] = mfma_bf16(vf, pfr1, Ov[1][mf]);
        }
        __builtin_amdgcn_s_setprio(0);
      }
    }

    // ---- write O^T (row=d=quad*4+reg within mf, col=q=l15) per half ----
    #pragma unroll
    for (int hh = 0; hh < 2; hh++) {
      float inv = 1.f / Ls[hh];
      size_t token = (size_t)b * 2048 + qt * 128 + hh * 64 + wave * 16 + l15;
      float* obase = attn + token * 4096 + h * 128 + quad * 4;
      #pragma unroll
      for (int mf = 0; mf < 8; mf++) {
        float4 v4 = make_float4(Ov[hh][mf][0] * inv, Ov[hh][mf][1] * inv,
                                Ov[hh][mf][2] * inv, Ov[hh][mf][3] * inv);
        *(float4*)(obase + mf * 16) = v4;
      }
    }
  }
}

extern "C" void kernel_launch(void* const* d_in, const int* in_sizes, int n_in,
                              void* d_out, int out_size, void* d_ws, size_t ws_size,
                              hipStream_t stream) {
  (void)in_sizes; (void)out_size;
  if (n_in < 6) return;
  const float* hs = (const float*)d_in[0];
  const float* Wq = (const float*)d_in[2];
  const float* Wk = (const float*)d_in[3];
  const float* Wv = (const float*)d_in[4];
  const float* Wo = (const float*)d_in[5];
  float* out = (float*)d_out;

  char* p = (char*)d_ws;
  size_t off = 0;
  auto take = [&](size_t bytes) { char* r = p + off; off += (bytes + 255) & ~(size_t)255; return r; };
  int8_t*   xq1  = (int8_t*)  take((size_t)4096 * 4096);
  float*    rs1  = (float*)   take(4096 * 4);
  int8_t*   wqkv = (int8_t*)  take((size_t)6144 * 4096);
  int8_t*   woq  = (int8_t*)  take((size_t)4096 * 4096);
  uint16_t* qb   = (uint16_t*)take((size_t)2 * 32 * 2048 * 128 * 2);
  uint16_t* kb   = (uint16_t*)take((size_t)2 * 8 * 2048 * 128 * 2);
  uint16_t* vb   = (uint16_t*)take((size_t)2 * 8 * 2048 * 128 * 2);
  uint16_t* vtb  = (uint16_t*)take((size_t)2 * 8 * 2048 * 128 * 2);
  float*    attn = (float*)   take((size_t)4096 * 4096 * 4);
  int8_t*   xq2  = (int8_t*)  take((size_t)4096 * 4096);
  float*    rs2  = (float*)   take(4096 * 4);
  double*   part = (double*)  take(2560 * 8);
  double*   sums = (double*)  take(256);
  if (off > ws_size) return;

  k_abssum_part<<<2560, 256, 0, stream>>>(Wq, Wk, Wv, Wo, part);
  k_reduce_sums<<<1, 256, 0, stream>>>(part, sums);
  k_quant_w_all<<<2560, 256, 0, stream>>>(Wq, Wk, Wv, Wo, wqkv, woq, sums);
  k_qact_f32<<<4096, 256, 0, stream>>>(hs, xq1, rs1);
  k_gemm_i8<0><<<dim3(48, 32), 256, 0, stream>>>(xq1, wqkv, rs1, sums, qb, kb, vb, (float*)nullptr);
  k_transpose_v<<<dim3(32, 2, 16), 256, 0, stream>>>(vb, vtb);
  k_attn<<<dim3(8, 64), 256, 0, stream>>>(qb, kb, vtb, attn);
  k_qact_f32<<<4096, 256, 0, stream>>>(attn, xq2, rs2);
  k_gemm_i8<1><<<dim3(32, 32), 256, 0, stream>>>(xq2, woq, rs2, sums,
                                                 (uint16_t*)nullptr, (uint16_t*)nullptr, (uint16_t*)nullptr, out);
}